// Round 1
// baseline (563.317 us; speedup 1.0000x reference)
//
#include <hip/hip_runtime.h>
#include <hip/hip_bf16.h>

#define SLEN 512
#define BATCH 256
#define NIN 300
#define KP 320
#define NG 256
#define NH 64
#define BM 128
#define BN 128
#define BK 64
#define LDP 72   // padded LDS row length (bf16) -> 144B rows, conflict-free b128 reads

typedef float f32x4 __attribute__((ext_vector_type(4)));
typedef short s16x8 __attribute__((ext_vector_type(8)));
typedef short s16x4 __attribute__((ext_vector_type(4)));

__device__ __forceinline__ short f2bf(float f) {
  union { float f; unsigned u; } v; v.f = f;
  unsigned r = v.u + 0x7fffu + ((v.u >> 16) & 1u);  // RNE
  return (short)(r >> 16);
}

// Build WcatT[n][k] (bf16, K padded to 320 with zeros) and bcat[n].
// Column n = g*64+h: h<32 -> W_pt0[:, g*32+h]; h>=32 -> 0.5*W_pt1[k/2, g*32+h-32].
__global__ void prep_w(const float* __restrict__ Wpt0, const float* __restrict__ bpt0,
                       const float* __restrict__ Wpt1, const float* __restrict__ bpt1,
                       short* __restrict__ WcatT, float* __restrict__ bcat) {
  int idx = blockIdx.x * 256 + threadIdx.x;
  if (idx < NG * KP) {
    int n = idx / KP, k = idx - n * KP;
    int g = n >> 6, h = n & 63;
    float w = 0.f;
    if (k < NIN) {
      if (h < 32) w = Wpt0[k * 128 + g * 32 + h];
      else        w = 0.5f * Wpt1[(k >> 1) * 128 + g * 32 + (h - 32)];
    }
    WcatT[idx] = f2bf(w);
  }
  if (idx < NG) {
    int g = idx >> 6, h = idx & 63;
    bcat[idx] = (h < 32) ? bpt0[g * 32 + h] : bpt1[g * 32 + h - 32];
  }
}

// C[row][n] = bf16(x[row]) @ WcatT^T + bcat   (row-chunk local)
__global__ __launch_bounds__(256) void gemm_i2h(
    const float* __restrict__ x, const short* __restrict__ WcatT,
    const float* __restrict__ bcat, float* __restrict__ C) {
  __shared__ short As[BM][LDP];
  __shared__ short Bs[BN][LDP];
  const int tid = threadIdx.x;
  const int m0 = blockIdx.x * BM;
  const int n0 = blockIdx.y * BN;
  const int lane = tid & 63;
  const int w = tid >> 6;
  const int wr = w >> 1, wc = w & 1;

  f32x4 acc[4][4];
#pragma unroll
  for (int m = 0; m < 4; ++m)
#pragma unroll
    for (int n = 0; n < 4; ++n) acc[m][n] = (f32x4){0.f, 0.f, 0.f, 0.f};

  const int arow_l = tid >> 4;        // 0..15
  const int acol   = (tid & 15) * 4;  // 0..60
  const int brow_l = tid >> 3;        // 0..31
  const int bcol   = (tid & 7) * 8;   // 0..56

  for (int k0 = 0; k0 < KP; k0 += BK) {
    // stage A: 128 rows x 64 cols, f32 -> bf16 (zero-pad k >= 300)
#pragma unroll
    for (int p = 0; p < 8; ++p) {
      int row = p * 16 + arow_l;
      int gk = k0 + acol;
      f32x4 v = (f32x4){0.f, 0.f, 0.f, 0.f};
      if (gk + 3 < NIN)  // 300 = 4*75 so vectors never straddle the boundary
        v = *reinterpret_cast<const f32x4*>(&x[(size_t)(m0 + row) * NIN + gk]);
      s16x4 sv;
      sv[0] = f2bf(v[0]); sv[1] = f2bf(v[1]); sv[2] = f2bf(v[2]); sv[3] = f2bf(v[3]);
      *reinterpret_cast<s16x4*>(&As[row][acol]) = sv;
    }
    // stage B (already bf16, transposed layout [n][k])
#pragma unroll
    for (int p = 0; p < 4; ++p) {
      int n = p * 32 + brow_l;
      s16x8 v = *reinterpret_cast<const s16x8*>(&WcatT[(size_t)(n0 + n) * KP + k0 + bcol]);
      *reinterpret_cast<s16x8*>(&Bs[n][bcol]) = v;
    }
    __syncthreads();
#pragma unroll
    for (int ks = 0; ks < 2; ++ks) {
      const int kk = ks * 32 + (lane >> 4) * 8;
      s16x8 a[4], b[4];
#pragma unroll
      for (int m = 0; m < 4; ++m)
        a[m] = *reinterpret_cast<const s16x8*>(&As[wr * 64 + m * 16 + (lane & 15)][kk]);
#pragma unroll
      for (int n = 0; n < 4; ++n)
        b[n] = *reinterpret_cast<const s16x8*>(&Bs[wc * 64 + n * 16 + (lane & 15)][kk]);
#pragma unroll
      for (int m = 0; m < 4; ++m)
#pragma unroll
        for (int n = 0; n < 4; ++n)
          acc[m][n] = __builtin_amdgcn_mfma_f32_16x16x32_bf16(a[m], b[n], acc[m][n], 0, 0, 0);
    }
    __syncthreads();
  }
  const int fc = lane & 15;
  const int fr = (lane >> 4) * 4;
#pragma unroll
  for (int n = 0; n < 4; ++n) {
    int col = n0 + wc * 64 + n * 16 + fc;
    float bias = bcat[col];
#pragma unroll
    for (int m = 0; m < 4; ++m) {
#pragma unroll
      for (int r = 0; r < 4; ++r) {
        int row = m0 + wr * 64 + m * 16 + fr + r;
        C[(size_t)row * NG + col] = acc[m][n][r] + bias;
      }
    }
  }
}

// One workgroup per batch row; thread n owns gate column n (W_glt[:,n] in VGPRs).
// Wave 0 (threads 0..63) owns the h/c state and the 3-wide decoder.
__global__ __launch_bounds__(256) void rec_seq(
    const float* __restrict__ i2h, const float* __restrict__ Wglt,
    const float* __restrict__ Wdec, const float* __restrict__ bdec,
    const float* __restrict__ h_in, const float* __restrict__ c_in,
    float* __restrict__ h_state, float* __restrict__ c_state,
    float* __restrict__ dec_out, float* __restrict__ hT_out, float* __restrict__ cT_out,
    int T, int is_last) {
  const int b = blockIdx.x;
  const int tid = threadIdx.x;
  __shared__ float h_lds[NH];
  __shared__ float act[NG];

  float wcol[NH];
#pragma unroll
  for (int k = 0; k < NH; ++k) wcol[k] = Wglt[k * NG + tid];

  float creg = 0.f, hreg = 0.f;
  float wd0 = 0.f, wd1 = 0.f, wd2 = 0.f, bd0 = 0.f, bd1 = 0.f, bd2 = 0.f;
  if (tid < NH) {
    creg = c_in[b * NH + tid];
    h_lds[tid] = h_in[b * NH + tid];
    wd0 = Wdec[tid * 3]; wd1 = Wdec[tid * 3 + 1]; wd2 = Wdec[tid * 3 + 2];
    bd0 = bdec[0]; bd1 = bdec[1]; bd2 = bdec[2];
  }
  __syncthreads();

  const float* ip = i2h + (size_t)b * NG + tid;
  float cur = ip[0];
  float nxt = (T > 1) ? ip[(size_t)NG * BATCH] : 0.f;
  const int is_g = ((tid >> 6) == 1);
  const float mm = is_g ? 2.f : 1.f;

  for (int s = 0; s < T; ++s) {
    float fut = 0.f;
    if (s + 2 < T) fut = ip[(size_t)(s + 2) * NG * BATCH];  // depth-2 prefetch (HBM latency)

    float a0 = 0.f, a1 = 0.f, a2 = 0.f, a3 = 0.f;
#pragma unroll
    for (int k = 0; k < NH; k += 4) {
      f32x4 h4 = *reinterpret_cast<const f32x4*>(&h_lds[k]);
      a0 += h4[0] * wcol[k];     a1 += h4[1] * wcol[k + 1];
      a2 += h4[2] * wcol[k + 2]; a3 += h4[3] * wcol[k + 3];
    }
    float pre = cur + ((a0 + a1) + (a2 + a3));
    // sigmoid for f,i,o; tanh (=2*sigmoid(2x)-1) for g; one exp either way
    float xx = fminf(fmaxf(pre, -30.f), 30.f);
    float e = __expf(-mm * xx);
    float y = 1.f / (1.f + e);
    act[tid] = is_g ? (2.f * y - 1.f) : y;
    __syncthreads();

    if (tid < NH) {
      float f_ = act[tid];
      float g_ = act[64 + tid];
      float i_ = act[128 + tid];
      float o_ = act[192 + tid];
      float c1 = f_ * creg + i_ * g_;
      creg = c1;
      float ct = fminf(fmaxf(c1, -15.f), 15.f);
      float e2 = __expf(-2.f * ct);
      float th = (1.f - e2) / (1.f + e2);
      float h1 = o_ * th;
      hreg = h1;
      h_lds[tid] = h1;
      float d0 = h1 * wd0, d1 = h1 * wd1, d2 = h1 * wd2;
#pragma unroll
      for (int off = 32; off; off >>= 1) {
        d0 += __shfl_xor(d0, off);
        d1 += __shfl_xor(d1, off);
        d2 += __shfl_xor(d2, off);
      }
      if (tid == 0) {
        float* dp = dec_out + ((size_t)s * BATCH + b) * 3;
        dp[0] = d0 + bd0; dp[1] = d1 + bd1; dp[2] = d2 + bd2;
      }
    }
    __syncthreads();
    cur = nxt; nxt = fut;
  }
  if (tid < NH) {
    h_state[b * NH + tid] = hreg;
    c_state[b * NH + tid] = creg;
    if (is_last) { hT_out[b * NH + tid] = hreg; cT_out[b * NH + tid] = creg; }
  }
}

extern "C" void kernel_launch(void* const* d_in, const int* in_sizes, int n_in,
                              void* d_out, int out_size, void* d_ws, size_t ws_size,
                              hipStream_t stream) {
  const float* x    = (const float*)d_in[0];
  const float* h0   = (const float*)d_in[1];
  const float* c0   = (const float*)d_in[2];
  const float* Wpt0 = (const float*)d_in[3];
  const float* bpt0 = (const float*)d_in[4];
  const float* Wpt1 = (const float*)d_in[5];
  const float* bpt1 = (const float*)d_in[6];
  const float* Wglt = (const float*)d_in[7];
  const float* Wdec = (const float*)d_in[8];
  const float* bdec = (const float*)d_in[9];
  float* out = (float*)d_out;

  char* ws = (char*)d_ws;
  short* WcatT   = (short*)(ws);            // 320*256*2 = 163840 B
  float* bcat    = (float*)(ws + 163840);   // 1 KB
  float* h_state = (float*)(ws + 196608);   // 64 KB
  float* c_state = (float*)(ws + 262144);   // 64 KB
  float* i2h     = (float*)(ws + 327680);   // chunked i2h buffer

  size_t avail = (ws_size > 327680) ? ws_size - 327680 : 0;
  int T = (int)(avail / ((size_t)BATCH * NG * 4));
  if (T > SLEN) T = SLEN;
  if (T < 1) T = 1;

  prep_w<<<dim3((NG * KP + 255) / 256), dim3(256), 0, stream>>>(
      Wpt0, bpt0, Wpt1, bpt1, WcatT, bcat);

  for (int t0 = 0; t0 < SLEN; t0 += T) {
    int Tc = (SLEN - t0 < T) ? (SLEN - t0) : T;
    dim3 g(Tc * BATCH / BM, NG / BN);
    gemm_i2h<<<g, dim3(256), 0, stream>>>(
        x + (size_t)t0 * BATCH * NIN, WcatT, bcat, i2h);
    rec_seq<<<dim3(BATCH), dim3(256), 0, stream>>>(
        i2h, Wglt, Wdec, bdec,
        (t0 == 0) ? h0 : h_state, (t0 == 0) ? c0 : c_state,
        h_state, c_state,
        out + (size_t)t0 * BATCH * 3,
        out + (size_t)SLEN * BATCH * 3,
        out + (size_t)SLEN * BATCH * 3 + BATCH * NH,
        Tc, (t0 + Tc >= SLEN) ? 1 : 0);
  }
}

// Round 2
// 439.212 us; speedup vs baseline: 1.2826x; 1.2826x over previous
//
#include <hip/hip_runtime.h>
#include <hip/hip_bf16.h>

#define SLEN 512
#define BATCH 256
#define NIN 300
#define KP 320
#define NG 256
#define NH 64
#define BM 128
#define BN 128
#define BK 64
#define LDP 72   // padded LDS row length (bf16) -> 144B rows, 2-way (free) b128 reads

typedef float f32x4 __attribute__((ext_vector_type(4)));
typedef short s16x8 __attribute__((ext_vector_type(8)));
typedef short s16x4 __attribute__((ext_vector_type(4)));

__device__ __forceinline__ short f2bf(float f) {
  union { float f; unsigned u; } v; v.f = f;
  unsigned r = v.u + 0x7fffu + ((v.u >> 16) & 1u);  // RNE
  return (short)(r >> 16);
}

// Build WcatT[n][k] (bf16, K padded to 320 with zeros) and bcat[n].
// Column n = g*64+h: h<32 -> W_pt0[:, g*32+h]; h>=32 -> 0.5*W_pt1[k/2, g*32+h-32].
__global__ void prep_w(const float* __restrict__ Wpt0, const float* __restrict__ bpt0,
                       const float* __restrict__ Wpt1, const float* __restrict__ bpt1,
                       short* __restrict__ WcatT, float* __restrict__ bcat) {
  int idx = blockIdx.x * 256 + threadIdx.x;
  if (idx < NG * KP) {
    int n = idx / KP, k = idx - n * KP;
    int g = n >> 6, h = n & 63;
    float w = 0.f;
    if (k < NIN) {
      if (h < 32) w = Wpt0[k * 128 + g * 32 + h];
      else        w = 0.5f * Wpt1[(k >> 1) * 128 + g * 32 + (h - 32)];
    }
    WcatT[idx] = f2bf(w);
  }
  if (idx < NG) {
    int g = idx >> 6, h = idx & 63;
    bcat[idx] = (h < 32) ? bpt0[g * 32 + h] : bpt1[g * 32 + h - 32];
  }
}

// C[row][n] = bf16(x[row]) @ WcatT^T + bcat   (row-chunk local)
__global__ __launch_bounds__(256) void gemm_i2h(
    const float* __restrict__ x, const short* __restrict__ WcatT,
    const float* __restrict__ bcat, float* __restrict__ C) {
  __shared__ short As[BM][LDP];
  __shared__ short Bs[BN][LDP];
  const int tid = threadIdx.x;
  const int m0 = blockIdx.x * BM;
  const int n0 = blockIdx.y * BN;
  const int lane = tid & 63;
  const int w = tid >> 6;
  const int wr = w >> 1, wc = w & 1;

  f32x4 acc[4][4];
#pragma unroll
  for (int m = 0; m < 4; ++m)
#pragma unroll
    for (int n = 0; n < 4; ++n) acc[m][n] = (f32x4){0.f, 0.f, 0.f, 0.f};

  const int arow_l = tid >> 4;        // 0..15
  const int acol   = (tid & 15) * 4;  // 0..60
  const int brow_l = tid >> 3;        // 0..31
  const int bcol   = (tid & 7) * 8;   // 0..56

  for (int k0 = 0; k0 < KP; k0 += BK) {
#pragma unroll
    for (int p = 0; p < 8; ++p) {
      int row = p * 16 + arow_l;
      int gk = k0 + acol;
      f32x4 v = (f32x4){0.f, 0.f, 0.f, 0.f};
      if (gk + 3 < NIN)  // 300 = 4*75 so vectors never straddle the boundary
        v = *reinterpret_cast<const f32x4*>(&x[(size_t)(m0 + row) * NIN + gk]);
      s16x4 sv;
      sv[0] = f2bf(v[0]); sv[1] = f2bf(v[1]); sv[2] = f2bf(v[2]); sv[3] = f2bf(v[3]);
      *reinterpret_cast<s16x4*>(&As[row][acol]) = sv;
    }
#pragma unroll
    for (int p = 0; p < 4; ++p) {
      int n = p * 32 + brow_l;
      s16x8 v = *reinterpret_cast<const s16x8*>(&WcatT[(size_t)(n0 + n) * KP + k0 + bcol]);
      *reinterpret_cast<s16x8*>(&Bs[n][bcol]) = v;
    }
    __syncthreads();
#pragma unroll
    for (int ks = 0; ks < 2; ++ks) {
      const int kk = ks * 32 + (lane >> 4) * 8;
      s16x8 a[4], b[4];
#pragma unroll
      for (int m = 0; m < 4; ++m)
        a[m] = *reinterpret_cast<const s16x8*>(&As[wr * 64 + m * 16 + (lane & 15)][kk]);
#pragma unroll
      for (int n = 0; n < 4; ++n)
        b[n] = *reinterpret_cast<const s16x8*>(&Bs[wc * 64 + n * 16 + (lane & 15)][kk]);
#pragma unroll
      for (int m = 0; m < 4; ++m)
#pragma unroll
        for (int n = 0; n < 4; ++n)
          acc[m][n] = __builtin_amdgcn_mfma_f32_16x16x32_bf16(a[m], b[n], acc[m][n], 0, 0, 0);
    }
    __syncthreads();
  }
  const int fc = lane & 15;
  const int fr = (lane >> 4) * 4;
#pragma unroll
  for (int n = 0; n < 4; ++n) {
    int col = n0 + wc * 64 + n * 16 + fc;
    float bias = bcat[col];
#pragma unroll
    for (int m = 0; m < 4; ++m) {
#pragma unroll
      for (int r = 0; r < 4; ++r) {
        int row = m0 + wr * 64 + m * 16 + fr + r;
        C[(size_t)row * NG + col] = acc[m][n][r] + bias;
      }
    }
  }
}

// One workgroup (256 thr = 4 waves) per batch row.
// Wave w, lane l: gate g = l>>4, hidden hidx = 16w + (l&15), gate column = g*64+hidx.
// Weights held in 64 VGPRs per thread (launch_bounds(256,1) -> no spill).
// One barrier per step; h double-buffered in LDS; gate exchange via 3 intra-wave shfl.
// Decoder removed from the loop: h1 streamed to hs[] for a separate decode pass.
__global__ __launch_bounds__(256, 1) void rec_seq(
    const float* __restrict__ i2h, const float* __restrict__ Wglt,
    const float* __restrict__ h_in, const float* __restrict__ c_in,
    float* __restrict__ h_state, float* __restrict__ c_state,
    float* __restrict__ hs_out, float* __restrict__ hT_out, float* __restrict__ cT_out,
    int T, int is_last) {
  const int b = blockIdx.x;
  const int tid = threadIdx.x;
  const int w = tid >> 6;
  const int l = tid & 63;
  const int g = l >> 4;
  const int hidx = w * 16 + (l & 15);
  const int col = g * 64 + hidx;
  __shared__ float h_lds[2][NH];

  float wcol[NH];
#pragma unroll
  for (int k = 0; k < NH; ++k) wcol[k] = Wglt[k * NG + col];

  float creg = 0.f;
  if (l < 16) creg = c_in[b * NH + hidx];
  if (tid < NH) h_lds[0][tid] = h_in[b * NH + tid];
  __syncthreads();

  const float* ip = i2h + (size_t)b * NG + col;
  float cur = ip[0];
  float nxt = (T > 1) ? ip[(size_t)NG * BATCH] : 0.f;
  const float mm = (g == 1) ? 2.f : 1.f;

  for (int s = 0; s < T; ++s) {
    float fut = 0.f;
    if (s + 2 < T) fut = ip[(size_t)(s + 2) * NG * BATCH];  // depth-2 prefetch

    const float* hb = h_lds[s & 1];
    float a0 = 0.f, a1 = 0.f, a2 = 0.f, a3 = 0.f;
#pragma unroll
    for (int k = 0; k < NH; k += 4) {
      f32x4 h4 = *reinterpret_cast<const f32x4*>(&hb[k]);
      a0 += h4[0] * wcol[k];     a1 += h4[1] * wcol[k + 1];
      a2 += h4[2] * wcol[k + 2]; a3 += h4[3] * wcol[k + 3];
    }
    float pre = cur + ((a0 + a1) + (a2 + a3));
    // sigmoid for f,i,o; tanh (=2*sigmoid(2x)-1) for g; one exp either way
    float xx = fminf(fmaxf(pre, -30.f), 30.f);
    float e = __expf(-mm * xx);
    float y = 1.f / (1.f + e);
    float act = (g == 1) ? (2.f * y - 1.f) : y;

    // lanes 0..15 (g==0, holding f) gather g,i,o from lanes +16,+32,+48
    float g_ = __shfl(act, l + 16);
    float i_ = __shfl(act, l + 32);
    float o_ = __shfl(act, l + 48);

    if (l < 16) {
      float c1 = act * creg + i_ * g_;
      creg = c1;
      float ct = fminf(fmaxf(c1, -15.f), 15.f);
      float e2 = __expf(-2.f * ct);
      float th = (1.f - e2) / (1.f + e2);
      float h1 = o_ * th;
      h_lds[(s + 1) & 1][hidx] = h1;
      hs_out[((size_t)s * BATCH + b) * NH + hidx] = h1;  // fire-and-forget
    }
    __syncthreads();
    cur = nxt; nxt = fut;
  }
  if (l < 16) {
    h_state[b * NH + hidx] = h_lds[T & 1][hidx];
    c_state[b * NH + hidx] = creg;
    if (is_last) {
      hT_out[b * NH + hidx] = h_lds[T & 1][hidx];
      cT_out[b * NH + hidx] = creg;
    }
  }
}

// decoded[idx][j] = hs[idx][:] @ Wdec[:,j] + bdec[j], idx = s*BATCH+b
__global__ __launch_bounds__(256) void decode(
    const float* __restrict__ hs, const float* __restrict__ Wdec,
    const float* __restrict__ bdec, float* __restrict__ out, int n) {
  __shared__ float wl[NH * 3];
  __shared__ float bl[3];
  const int tid = threadIdx.x;
  if (tid < NH * 3) wl[tid] = Wdec[tid];
  if (tid < 3) bl[tid] = bdec[tid];
  __syncthreads();
  int idx = blockIdx.x * 256 + tid;
  if (idx >= n) return;
  const float* hp = hs + (size_t)idx * NH;
  float d0 = 0.f, d1 = 0.f, d2 = 0.f;
#pragma unroll
  for (int k = 0; k < NH; k += 4) {
    f32x4 h4 = *reinterpret_cast<const f32x4*>(&hp[k]);
#pragma unroll
    for (int j = 0; j < 4; ++j) {
      d0 += h4[j] * wl[(k + j) * 3 + 0];
      d1 += h4[j] * wl[(k + j) * 3 + 1];
      d2 += h4[j] * wl[(k + j) * 3 + 2];
    }
  }
  out[(size_t)idx * 3 + 0] = d0 + bl[0];
  out[(size_t)idx * 3 + 1] = d1 + bl[1];
  out[(size_t)idx * 3 + 2] = d2 + bl[2];
}

extern "C" void kernel_launch(void* const* d_in, const int* in_sizes, int n_in,
                              void* d_out, int out_size, void* d_ws, size_t ws_size,
                              hipStream_t stream) {
  const float* x    = (const float*)d_in[0];
  const float* h0   = (const float*)d_in[1];
  const float* c0   = (const float*)d_in[2];
  const float* Wpt0 = (const float*)d_in[3];
  const float* bpt0 = (const float*)d_in[4];
  const float* Wpt1 = (const float*)d_in[5];
  const float* bpt1 = (const float*)d_in[6];
  const float* Wglt = (const float*)d_in[7];
  const float* Wdec = (const float*)d_in[8];
  const float* bdec = (const float*)d_in[9];
  float* out = (float*)d_out;

  char* ws = (char*)d_ws;
  short* WcatT   = (short*)(ws);            // 320*256*2 = 163840 B
  float* bcat    = (float*)(ws + 163840);   // 1 KB
  float* h_state = (float*)(ws + 196608);   // 64 KB
  float* c_state = (float*)(ws + 262144);   // 64 KB
  const size_t base = 327680;

  // per-step chunk bytes: i2h (256*256*4) + hs (256*64*4)
  const size_t i2h_step = (size_t)BATCH * NG * 4;
  const size_t hs_step  = (size_t)BATCH * NH * 4;
  size_t avail = (ws_size > base) ? ws_size - base : 0;
  int T = (int)(avail / (i2h_step + hs_step));
  if (T > SLEN) T = SLEN;
  if (T < 1) T = 1;

  float* i2h = (float*)(ws + base);
  float* hs  = (float*)(ws + base + (size_t)T * i2h_step);

  prep_w<<<dim3((NG * KP + 255) / 256), dim3(256), 0, stream>>>(
      Wpt0, bpt0, Wpt1, bpt1, WcatT, bcat);

  for (int t0 = 0; t0 < SLEN; t0 += T) {
    int Tc = (SLEN - t0 < T) ? (SLEN - t0) : T;
    dim3 g(Tc * BATCH / BM, NG / BN);
    gemm_i2h<<<g, dim3(256), 0, stream>>>(
        x + (size_t)t0 * BATCH * NIN, WcatT, bcat, i2h);
    rec_seq<<<dim3(BATCH), dim3(256), 0, stream>>>(
        i2h, Wglt,
        (t0 == 0) ? h0 : h_state, (t0 == 0) ? c0 : c_state,
        h_state, c_state, hs,
        out + (size_t)SLEN * BATCH * 3,
        out + (size_t)SLEN * BATCH * 3 + BATCH * NH,
        Tc, (t0 + Tc >= SLEN) ? 1 : 0);
    decode<<<dim3((Tc * BATCH + 255) / 256), dim3(256), 0, stream>>>(
        hs, Wdec, bdec, out + (size_t)t0 * BATCH * 3, Tc * BATCH);
  }
}